// Round 5
// baseline (1400.237 us; speedup 1.0000x reference)
//
#include <hip/hip_runtime.h>

#define NB 8
#define TT 24
#define NN 4000
#define FF 32
#define HH 128
#define EE 64000

typedef float f32x4 __attribute__((ext_vector_type(4)));
typedef short bf16x8 __attribute__((ext_vector_type(8)));
#define MFMA16(a, b, c) __builtin_amdgcn_mfma_f32_16x16x32_bf16(a, b, c, 0, 0, 0)

__device__ __forceinline__ float fsig(float x) { return 1.0f / (1.0f + __expf(-x)); }
__device__ __forceinline__ float ftanh(float x) { float e = __expf(2.0f * x); return 1.0f - 2.0f / (e + 1.0f); }

// round-to-nearest-even fp32 -> bf16; returns bits, sets *hif to the bf16 value as fp32
__device__ __forceinline__ unsigned short rne16(float x, float* hif) {
  unsigned u = __float_as_uint(x);
  unsigned r = (u + 0x7FFFu + ((u >> 16) & 1u)) >> 16;
  *hif = __uint_as_float(r << 16);
  return (unsigned short)r;
}

// ---------- setup: pack weights into MFMA fragment order (hi/lo split), combine bias, init deg ----------
// Frag pack (A- and B-frag lane layouts are symmetric; same pack serves A=W):
// Wbh flat p: e=p&7, l=(p>>3)&63, ks=(p>>9)&3, nt=p>>11
//   gate = nt*16 + (l&15), k = ks*32 + (l>>4)*8 + e;  src = W_hh[gate*128 + k]
// Wbi flat p: e=p&7, l=(p>>3)&63, nt=p>>9
//   gate = nt*16 + (l&15), k = (l>>4)*8 + e;          src = W_ih[gate*32 + k]
__global__ void setup_kernel(const float* __restrict__ W_ih, const float* __restrict__ W_hh,
                             const float* __restrict__ b_ih, const float* __restrict__ b_hh,
                             const float* __restrict__ gcn_W,
                             unsigned short* __restrict__ Wbh_hi, unsigned short* __restrict__ Wbh_lo,
                             unsigned short* __restrict__ Wbi_hi, unsigned short* __restrict__ Wbi_lo,
                             float* __restrict__ gcn_WT, float* __restrict__ bias,
                             float* __restrict__ deg) {
  int idx = blockIdx.x * 256 + threadIdx.x;
  if (idx < 65536) {
    int e = idx & 7, l = (idx >> 3) & 63, ks = (idx >> 9) & 3, nt = idx >> 11;
    int gate = nt * 16 + (l & 15);
    int k = ks * 32 + (l >> 4) * 8 + e;
    float wv = W_hh[gate * 128 + k];
    float hif, d;
    unsigned short hb = rne16(wv, &hif);
    unsigned short lb = rne16(wv - hif, &d);
    Wbh_hi[idx] = hb;
    Wbh_lo[idx] = lb;
  } else if (idx < 65536 + 16384) {
    int p = idx - 65536;
    int e = p & 7, l = (p >> 3) & 63, nt = p >> 9;
    int gate = nt * 16 + (l & 15);
    int k = (l >> 4) * 8 + e;
    float wv = W_ih[gate * 32 + k];
    float hif, d;
    unsigned short hb = rne16(wv, &hif);
    unsigned short lb = rne16(wv - hif, &d);
    Wbi_hi[p] = hb;
    Wbi_lo[p] = lb;
  } else if (idx < 65536 + 16384 + 16384) {
    int p = idx - 65536 - 16384;
    int g = p & 127, k = p >> 7;
    gcn_WT[p] = gcn_W[g * 128 + k];
  } else if (idx < 65536 + 16384 + 16384 + 512) {
    int g = idx - (65536 + 16384 + 16384);
    bias[g] = b_ih[g] + b_hh[g];
  } else if (idx < 65536 + 16384 + 16384 + 512 + NN) {
    int n = idx - (65536 + 16384 + 16384 + 512);
    deg[n] = 1.0f;  // self-loop
  }
}

// ---------- LSTM via split-bf16 MFMA, swapped operands: D[gate][seq] ----------
// 8 waves, 32 seqs/block. Wave w owns gate-tiles {g*8+w} (j-cols [16w,16w+16)).
// Lane (col,kc): owns seqs {col, 16+col}, j-cols j0..j0+3 (j0 = 16w+4kc) -> packed b64 LDS writes.
__global__ __launch_bounds__(512, 4) void lstm_kernel(
    const float* __restrict__ x,             // [B,T,N,F]
    const unsigned short* __restrict__ Wbh_hi, const unsigned short* __restrict__ Wbh_lo,
    const unsigned short* __restrict__ Wbi_hi, const unsigned short* __restrict__ Wbi_lo,
    const float* __restrict__ bias,          // [512] combined
    float* __restrict__ h_out)               // [B*N, H] fp32
{
  __shared__ unsigned short hbuf[2][2][32 * 128];  // [buf][hi/lo][seq*128+j] : 32 KB
  const int tid = threadIdx.x;
  const int w = tid >> 6, l = tid & 63;
  const int col = l & 15, kc = l >> 4;
  const int j0 = 16 * w + 4 * kc;
  const int blk = blockIdx.x;
  const int b = blk / (NN / 32);
  const int n0 = (blk % (NN / 32)) * 32;
  const int swz = (col & 7) << 4;

  {
    unsigned short* p0 = &hbuf[0][0][0];
    for (int i = tid; i < 2 * 32 * 128; i += 512) p0[i] = 0;
  }

  float c[2][4];
#pragma unroll
  for (int sq = 0; sq < 2; ++sq)
#pragma unroll
    for (int r = 0; r < 4; ++r) c[sq][r] = 0.0f;

  __syncthreads();

  for (int t = 0; t < TT; ++t) {
    const char* hr_hi = (const char*)&hbuf[t & 1][0][0];
    const char* hr_lo = (const char*)&hbuf[t & 1][1][0];
    char* hw_hi = (char*)&hbuf[(t + 1) & 1][0][0];
    char* hw_lo = (char*)&hbuf[(t + 1) & 1][1][0];

    // ---- x(t) B-frags: lane holds x[seq=16sq+col][f = 4kc*2 .. +8], split to bf16 hi/lo ----
    bf16x8 xh[2], xl[2];
#pragma unroll
    for (int sq = 0; sq < 2; ++sq) {
      const float* xb = x + (((size_t)b * TT + t) * NN + (n0 + 16 * sq + col)) * FF + kc * 8;
      float4 p0 = *(const float4*)xb;
      float4 p1 = *(const float4*)(xb + 4);
      float xf[8] = {p0.x, p0.y, p0.z, p0.w, p1.x, p1.y, p1.z, p1.w};
#pragma unroll
      for (int e = 0; e < 8; ++e) {
        float hif, d;
        xh[sq][e] = (short)rne16(xf[e], &hif);
        xl[sq][e] = (short)rne16(xf[e] - hif, &d);
      }
    }

    f32x4 acc[2][4];
#pragma unroll
    for (int sq = 0; sq < 2; ++sq)
#pragma unroll
      for (int g = 0; g < 4; ++g) acc[sq][g] = (f32x4){0.f, 0.f, 0.f, 0.f};

    // ---- recurrence: W_hh(A) x h(B), split-bf16 ----
#pragma unroll
    for (int ks = 0; ks < 4; ++ks) {
      bf16x8 bh[2], bl[2];
#pragma unroll
      for (int sq = 0; sq < 2; ++sq) {
        int off = ((16 * sq + col) * 256 + ks * 64 + kc * 16) ^ swz;
        bh[sq] = *(const bf16x8*)(hr_hi + off);
        bl[sq] = *(const bf16x8*)(hr_lo + off);
      }
#pragma unroll
      for (int g = 0; g < 4; ++g) {
        size_t wo = ((size_t)((g * 8 + w) * 4 + ks) * 64 + l) * 8;
        bf16x8 wh = *(const bf16x8*)(Wbh_hi + wo);
        bf16x8 wl = *(const bf16x8*)(Wbh_lo + wo);
#pragma unroll
        for (int sq = 0; sq < 2; ++sq) {
          acc[sq][g] = MFMA16(wh, bh[sq], acc[sq][g]);
          acc[sq][g] = MFMA16(wh, bl[sq], acc[sq][g]);
          acc[sq][g] = MFMA16(wl, bh[sq], acc[sq][g]);
        }
      }
    }

    // ---- input projection: W_ih(A) x x(B) ----
#pragma unroll
    for (int g = 0; g < 4; ++g) {
      size_t wo = ((size_t)(g * 8 + w) * 64 + l) * 8;
      bf16x8 wh = *(const bf16x8*)(Wbi_hi + wo);
      bf16x8 wl = *(const bf16x8*)(Wbi_lo + wo);
#pragma unroll
      for (int sq = 0; sq < 2; ++sq) {
        acc[sq][g] = MFMA16(wh, xh[sq], acc[sq][g]);
        acc[sq][g] = MFMA16(wh, xl[sq], acc[sq][g]);
        acc[sq][g] = MFMA16(wl, xh[sq], acc[sq][g]);
      }
    }

    // ---- gates (i,f,g,o) + state update; packed b64 writes of split h ----
    f32x4 bq[4];
#pragma unroll
    for (int g = 0; g < 4; ++g) bq[g] = *(const f32x4*)(bias + g * 128 + j0);

#pragma unroll
    for (int sq = 0; sq < 2; ++sq) {
      unsigned long long phi = 0ull, plo = 0ull;
      float hv[4];
#pragma unroll
      for (int r = 0; r < 4; ++r) {
        float iv = fsig(acc[sq][0][r] + bq[0][r]);
        float fv = fsig(acc[sq][1][r] + bq[1][r]);
        float gv = ftanh(acc[sq][2][r] + bq[2][r]);
        float ov = fsig(acc[sq][3][r] + bq[3][r]);
        float cc = fv * c[sq][r] + iv * gv;
        c[sq][r] = cc;
        float hh = ov * ftanh(cc);
        hv[r] = hh;
        float hif, d;
        unsigned short hb = rne16(hh, &hif);
        unsigned short lb = rne16(hh - hif, &d);
        phi |= (unsigned long long)hb << (16 * r);
        plo |= (unsigned long long)lb << (16 * r);
      }
      int woff = ((16 * sq + col) * 256 + j0 * 2) ^ swz;
      *(unsigned long long*)(hw_hi + woff) = phi;
      *(unsigned long long*)(hw_lo + woff) = plo;
      if (t == TT - 1) {
        *(float4*)&h_out[((size_t)(b * NN + n0 + 16 * sq + col)) * HH + j0] =
            make_float4(hv[0], hv[1], hv[2], hv[3]);
      }
    }
    __syncthreads();
  }
}

// ---------- GCN ----------
__global__ void deg_kernel(const int* __restrict__ ei, float* __restrict__ deg) {
  int e = blockIdx.x * 256 + threadIdx.x;
  if (e < EE) atomicAdd(&deg[ei[EE + e]], 1.0f);  // dst row
}

__global__ void dinv_kernel(const float* __restrict__ deg, float* __restrict__ dinv) {
  int n = blockIdx.x * 256 + threadIdx.x;
  if (n < NN) dinv[n] = 1.0f / sqrtf(deg[n]);  // deg >= 1 (self loop)
}

// xw[b,n,g] = sum_k h[b,n,k] * gcn_W[g,k]  ; 8 rows per block
__global__ __launch_bounds__(128) void xw_kernel(const float* __restrict__ h,
                                                 const float* __restrict__ gcn_WT,
                                                 float* __restrict__ xw) {
  const int r0 = blockIdx.x * 8;
  const int g = threadIdx.x;
  __shared__ float hs[8][HH];
  for (int m = 0; m < 8; ++m) hs[m][g] = h[(size_t)(r0 + m) * HH + g];
  __syncthreads();
  float acc[8] = {0, 0, 0, 0, 0, 0, 0, 0};
#pragma unroll 4
  for (int k = 0; k < HH; ++k) {
    float w = gcn_WT[k * HH + g];
#pragma unroll
    for (int m = 0; m < 8; ++m) acc[m] += hs[m][k] * w;
  }
  for (int m = 0; m < 8; ++m) xw[(size_t)(r0 + m) * HH + g] = acc[m];
}

// scatter: agg[b,dst,:] += xw[b,src,:] * norm(e); thread = (edge, channel)
__global__ void scatter_kernel(const int* __restrict__ ei, const float* __restrict__ xw,
                               const float* __restrict__ dinv, float* __restrict__ agg) {
  int gid = blockIdx.x * 256 + threadIdx.x;
  int e = gid >> 7;
  int jj = gid & 127;
  if (e >= EE) return;
  int s = ei[e];
  int d = ei[EE + e];
  float nrm = dinv[s] * dinv[d];
#pragma unroll
  for (int b = 0; b < NB; ++b) {
    float v = xw[((size_t)b * NN + s) * HH + jj] * nrm;
    atomicAdd(&agg[((size_t)b * NN + d) * HH + jj], v);
  }
}

// final: add self-loop + bias, relu, two dot heads. one wave per row.
__global__ __launch_bounds__(256) void final_kernel(
    const float* __restrict__ agg, const float* __restrict__ xw, const float* __restrict__ dinv,
    const float* __restrict__ gcn_b, const float* __restrict__ fcw_c, const float* __restrict__ fcb_c,
    const float* __restrict__ fcw_i, const float* __restrict__ fcb_i, float* __restrict__ out) {
  int row = blockIdx.x * 4 + (threadIdx.x >> 6);
  int lane = threadIdx.x & 63;
  int n = row % NN;
  float sn = dinv[n] * dinv[n];
  float sc = 0.0f, si = 0.0f;
  for (int jj = lane; jj < HH; jj += 64) {
    float v = agg[(size_t)row * HH + jj] + xw[(size_t)row * HH + jj] * sn + gcn_b[jj];
    v = fmaxf(v, 0.0f);
    sc += v * fcw_c[jj];
    si += v * fcw_i[jj];
  }
#pragma unroll
  for (int off = 32; off > 0; off >>= 1) {
    sc += __shfl_down(sc, off);
    si += __shfl_down(si, off);
  }
  if (lane == 0) {
    out[row] = sc + fcb_c[0];
    out[NB * NN + row] = si + fcb_i[0];
  }
}

extern "C" void kernel_launch(void* const* d_in, const int* in_sizes, int n_in,
                              void* d_out, int out_size, void* d_ws, size_t ws_size,
                              hipStream_t stream) {
  const float* x     = (const float*)d_in[0];
  const int*   ei    = (const int*)d_in[1];
  const float* W_ih  = (const float*)d_in[2];
  const float* W_hh  = (const float*)d_in[3];
  const float* b_ih  = (const float*)d_in[4];
  const float* b_hh  = (const float*)d_in[5];
  const float* gcn_W = (const float*)d_in[6];
  const float* gcn_b = (const float*)d_in[7];
  const float* fcw_c = (const float*)d_in[8];
  const float* fcb_c = (const float*)d_in[9];
  const float* fcw_i = (const float*)d_in[10];
  const float* fcb_i = (const float*)d_in[11];
  float* out = (float*)d_out;

  char* cur = (char*)d_ws;
  unsigned short* Wbh_hi = (unsigned short*)cur; cur += 65536 * 2;
  unsigned short* Wbh_lo = (unsigned short*)cur; cur += 65536 * 2;
  unsigned short* Wbi_hi = (unsigned short*)cur; cur += 16384 * 2;
  unsigned short* Wbi_lo = (unsigned short*)cur; cur += 16384 * 2;
  float* gcn_WT = (float*)cur; cur += 16384 * 4;
  float* bias   = (float*)cur; cur += 512 * 4;
  float* deg    = (float*)cur; cur += 4000 * 4;
  float* dinv   = (float*)cur; cur += 4000 * 4;
  float* h_all  = (float*)cur; cur += (size_t)4096000 * 4;
  float* xw     = (float*)cur; cur += (size_t)4096000 * 4;
  float* agg    = (float*)cur; cur += (size_t)4096000 * 4;

  setup_kernel<<<402, 256, 0, stream>>>(W_ih, W_hh, b_ih, b_hh, gcn_W,
                                        Wbh_hi, Wbh_lo, Wbi_hi, Wbi_lo,
                                        gcn_WT, bias, deg);
  hipMemsetAsync(agg, 0, (size_t)4096000 * sizeof(float), stream);
  lstm_kernel<<<(NB * NN) / 32, 512, 0, stream>>>(x, Wbh_hi, Wbh_lo, Wbi_hi, Wbi_lo,
                                                  bias, h_all);
  deg_kernel<<<EE / 256, 256, 0, stream>>>(ei, deg);
  dinv_kernel<<<(NN + 255) / 256, 256, 0, stream>>>(deg, dinv);
  xw_kernel<<<(NB * NN) / 8, 128, 0, stream>>>(h_all, gcn_WT, xw);
  scatter_kernel<<<(EE * 128) / 256, 256, 0, stream>>>(ei, xw, dinv, agg);
  final_kernel<<<(NB * NN) / 4, 256, 0, stream>>>(agg, xw, dinv, gcn_b, fcw_c, fcb_c,
                                                  fcw_i, fcb_i, out);
}

// Round 6
// 932.998 us; speedup vs baseline: 1.5008x; 1.5008x over previous
//
#include <hip/hip_runtime.h>

#define NB 8
#define TT 24
#define NN 4000
#define FF 32
#define HH 128
#define EE 64000

typedef float f32x4 __attribute__((ext_vector_type(4)));
typedef short bf16x8 __attribute__((ext_vector_type(8)));
#define MFMA16(a, b, c) __builtin_amdgcn_mfma_f32_16x16x32_bf16(a, b, c, 0, 0, 0)

__device__ __forceinline__ float fsig(float x) { return 1.0f / (1.0f + __expf(-x)); }
__device__ __forceinline__ float ftanh(float x) { float e = __expf(2.0f * x); return 1.0f - 2.0f / (e + 1.0f); }

// round-to-nearest-even fp32 -> bf16; returns bits, sets *hif to the bf16 value as fp32
__device__ __forceinline__ unsigned short rne16(float x, float* hif) {
  unsigned u = __float_as_uint(x);
  unsigned r = (u + 0x7FFFu + ((u >> 16) & 1u)) >> 16;
  *hif = __uint_as_float(r << 16);
  return (unsigned short)r;
}

// ---------- setup: pack weights into MFMA fragment order (hi/lo split), combine bias, init deg ----------
// Wbh flat p: e=p&7, l=(p>>3)&63, ks=(p>>9)&3, nt=p>>11
//   gate = nt*16 + (l&15), k = ks*32 + (l>>4)*8 + e;  src = W_hh[gate*128 + k]
// Wbi flat p: e=p&7, l=(p>>3)&63, nt=p>>9
//   gate = nt*16 + (l&15), k = (l>>4)*8 + e;          src = W_ih[gate*32 + k]
__global__ void setup_kernel(const float* __restrict__ W_ih, const float* __restrict__ W_hh,
                             const float* __restrict__ b_ih, const float* __restrict__ b_hh,
                             const float* __restrict__ gcn_W,
                             unsigned short* __restrict__ Wbh_hi, unsigned short* __restrict__ Wbh_lo,
                             unsigned short* __restrict__ Wbi_hi, unsigned short* __restrict__ Wbi_lo,
                             float* __restrict__ gcn_WT, float* __restrict__ bias,
                             float* __restrict__ deg) {
  int idx = blockIdx.x * 256 + threadIdx.x;
  if (idx < 65536) {
    int e = idx & 7, l = (idx >> 3) & 63, ks = (idx >> 9) & 3, nt = idx >> 11;
    int gate = nt * 16 + (l & 15);
    int k = ks * 32 + (l >> 4) * 8 + e;
    float wv = W_hh[gate * 128 + k];
    float hif, d;
    unsigned short hb = rne16(wv, &hif);
    unsigned short lb = rne16(wv - hif, &d);
    Wbh_hi[idx] = hb;
    Wbh_lo[idx] = lb;
  } else if (idx < 65536 + 16384) {
    int p = idx - 65536;
    int e = p & 7, l = (p >> 3) & 63, nt = p >> 9;
    int gate = nt * 16 + (l & 15);
    int k = (l >> 4) * 8 + e;
    float wv = W_ih[gate * 32 + k];
    float hif, d;
    unsigned short hb = rne16(wv, &hif);
    unsigned short lb = rne16(wv - hif, &d);
    Wbi_hi[p] = hb;
    Wbi_lo[p] = lb;
  } else if (idx < 65536 + 16384 + 16384) {
    int p = idx - 65536 - 16384;
    int g = p & 127, k = p >> 7;
    gcn_WT[p] = gcn_W[g * 128 + k];
  } else if (idx < 65536 + 16384 + 16384 + 512) {
    int g = idx - (65536 + 16384 + 16384);
    bias[g] = b_ih[g] + b_hh[g];
  } else if (idx < 65536 + 16384 + 16384 + 512 + NN) {
    int n = idx - (65536 + 16384 + 16384 + 512);
    deg[n] = 1.0f;  // self-loop
  }
}

// ---------- LSTM via split-bf16 MFMA, swapped operands: D[gate][seq] ----------
// 8 waves, 64 seqs/block (4 seq-tiles). Wave w owns gates {128g + 16w + [0,16)} for g=0..3.
// Lane (col,kc): seqs {16sq+col}, j-cols j0..j0+3 (j0=16w+4kc).
// LDS h layout: row = local seq (256B of bf16), 16B-chunk index XOR (row&15) -> conflict-free.
__global__ __launch_bounds__(512) void lstm_kernel(
    const float* __restrict__ x,             // [B,T,N,F]
    const unsigned short* __restrict__ Wbh_hi, const unsigned short* __restrict__ Wbh_lo,
    const unsigned short* __restrict__ Wbi_hi, const unsigned short* __restrict__ Wbi_lo,
    const float* __restrict__ bias,          // [512] combined
    float* __restrict__ h_out)               // [B*N, H] fp32
{
  __shared__ unsigned short hbuf[2][2][64 * 128];  // [buf][hi/lo][row*128+j] : 64 KB
  const int tid = threadIdx.x;
  const int w = tid >> 6, l = tid & 63;
  const int col = l & 15, kc = l >> 4;
  const int j0 = 16 * w + 4 * kc;
  const int r0 = blockIdx.x * 64;

  // zero h(0) buffer (both splits)
  {
    uint4* p0 = (uint4*)&hbuf[0][0][0];
    for (int i = tid; i < 2048; i += 512) p0[i] = make_uint4(0, 0, 0, 0);
  }

  // per-lane x bases (rows may straddle batch boundary; t-coefficient is uniform)
  size_t xbase[4];
  int rowg[4];
#pragma unroll
  for (int sq = 0; sq < 4; ++sq) {
    int r = r0 + 16 * sq + col;
    rowg[sq] = r;
    int bl = r / NN, nl = r - bl * NN;
    xbase[sq] = (size_t)bl * ((size_t)TT * NN * FF) + (size_t)nl * FF + kc * 8;
  }

  f32x4 bq[4];
#pragma unroll
  for (int g = 0; g < 4; ++g) bq[g] = *(const f32x4*)(bias + g * 128 + j0);

  float c[4][4];
#pragma unroll
  for (int sq = 0; sq < 4; ++sq)
#pragma unroll
    for (int r = 0; r < 4; ++r) c[sq][r] = 0.0f;

  __syncthreads();

  for (int t = 0; t < TT; ++t) {
    const char* hr_hi = (const char*)&hbuf[t & 1][0][0];
    const char* hr_lo = (const char*)&hbuf[t & 1][1][0];
    char* hw_hi = (char*)&hbuf[(t + 1) & 1][0][0];
    char* hw_lo = (char*)&hbuf[(t + 1) & 1][1][0];

    // ---- issue x(t) loads early (used only after the hh MFMA block) ----
    float4 xr[4][2];
#pragma unroll
    for (int sq = 0; sq < 4; ++sq) {
      const float* xb = x + xbase[sq] + (size_t)t * (NN * FF);
      xr[sq][0] = *(const float4*)xb;
      xr[sq][1] = *(const float4*)(xb + 4);
    }

    f32x4 acc[4][4];
#pragma unroll
    for (int sq = 0; sq < 4; ++sq)
#pragma unroll
      for (int g = 0; g < 4; ++g) acc[sq][g] = (f32x4){0.f, 0.f, 0.f, 0.f};

    // ---- recurrence: W_hh(A) x h(B), split-bf16 (3 MFMA per tile-pair) ----
#pragma unroll
    for (int ks = 0; ks < 4; ++ks) {
      bf16x8 bh[4], bl_[4];
#pragma unroll
      for (int sq = 0; sq < 4; ++sq) {
        int off = (16 * sq + col) * 256 + (((4 * ks + kc) ^ col) << 4);
        bh[sq] = *(const bf16x8*)(hr_hi + off);
        bl_[sq] = *(const bf16x8*)(hr_lo + off);
      }
#pragma unroll
      for (int g = 0; g < 4; ++g) {
        size_t wo = ((size_t)((g * 8 + w) * 4 + ks) * 64 + l) * 8;
        bf16x8 wh = *(const bf16x8*)(Wbh_hi + wo);
        bf16x8 wl = *(const bf16x8*)(Wbh_lo + wo);
#pragma unroll
        for (int sq = 0; sq < 4; ++sq) {
          acc[sq][g] = MFMA16(wh, bh[sq], acc[sq][g]);
          acc[sq][g] = MFMA16(wh, bl_[sq], acc[sq][g]);
          acc[sq][g] = MFMA16(wl, bh[sq], acc[sq][g]);
        }
      }
    }

    // ---- split x to bf16 hi/lo ----
    bf16x8 xh[4], xl[4];
#pragma unroll
    for (int sq = 0; sq < 4; ++sq) {
      float xf[8] = {xr[sq][0].x, xr[sq][0].y, xr[sq][0].z, xr[sq][0].w,
                     xr[sq][1].x, xr[sq][1].y, xr[sq][1].z, xr[sq][1].w};
#pragma unroll
      for (int e = 0; e < 8; ++e) {
        float hif, d;
        xh[sq][e] = (short)rne16(xf[e], &hif);
        xl[sq][e] = (short)rne16(xf[e] - hif, &d);
      }
    }

    // ---- input projection: W_ih(A) x x(B) ----
#pragma unroll
    for (int g = 0; g < 4; ++g) {
      size_t wo = ((size_t)(g * 8 + w) * 64 + l) * 8;
      bf16x8 wh = *(const bf16x8*)(Wbi_hi + wo);
      bf16x8 wl = *(const bf16x8*)(Wbi_lo + wo);
#pragma unroll
      for (int sq = 0; sq < 4; ++sq) {
        acc[sq][g] = MFMA16(wh, xh[sq], acc[sq][g]);
        acc[sq][g] = MFMA16(wh, xl[sq], acc[sq][g]);
        acc[sq][g] = MFMA16(wl, xh[sq], acc[sq][g]);
      }
    }

    // ---- gates (i,f,g,o) + state update; swizzled b64 writes of split h ----
#pragma unroll
    for (int sq = 0; sq < 4; ++sq) {
      unsigned long long phi = 0ull, plo = 0ull;
      float hv[4];
#pragma unroll
      for (int r = 0; r < 4; ++r) {
        float iv = fsig(acc[sq][0][r] + bq[0][r]);
        float fv = fsig(acc[sq][1][r] + bq[1][r]);
        float gv = ftanh(acc[sq][2][r] + bq[2][r]);
        float ov = fsig(acc[sq][3][r] + bq[3][r]);
        float cc = fv * c[sq][r] + iv * gv;
        c[sq][r] = cc;
        float hh = ov * ftanh(cc);
        hv[r] = hh;
        float hif, d;
        unsigned short hb = rne16(hh, &hif);
        unsigned short lb = rne16(hh - hif, &d);
        phi |= (unsigned long long)hb << (16 * r);
        plo |= (unsigned long long)lb << (16 * r);
      }
      int row = 16 * sq + col;
      int cs = ((2 * w + (kc >> 1)) ^ col);
      int woff = row * 256 + cs * 16 + 8 * (kc & 1);
      *(unsigned long long*)(hw_hi + woff) = phi;
      *(unsigned long long*)(hw_lo + woff) = plo;
      if (t == TT - 1) {
        *(float4*)&h_out[(size_t)rowg[sq] * HH + j0] =
            make_float4(hv[0], hv[1], hv[2], hv[3]);
      }
    }
    __syncthreads();
  }
}

// ---------- GCN ----------
__global__ void deg_kernel(const int* __restrict__ ei, float* __restrict__ deg) {
  int e = blockIdx.x * 256 + threadIdx.x;
  if (e < EE) atomicAdd(&deg[ei[EE + e]], 1.0f);  // dst row
}

__global__ void dinv_kernel(const float* __restrict__ deg, float* __restrict__ dinv) {
  int n = blockIdx.x * 256 + threadIdx.x;
  if (n < NN) dinv[n] = 1.0f / sqrtf(deg[n]);  // deg >= 1 (self loop)
}

// xw[b,n,g] = sum_k h[b,n,k] * gcn_W[g,k]  ; 8 rows per block
__global__ __launch_bounds__(128) void xw_kernel(const float* __restrict__ h,
                                                 const float* __restrict__ gcn_WT,
                                                 float* __restrict__ xw) {
  const int r0 = blockIdx.x * 8;
  const int g = threadIdx.x;
  __shared__ float hs[8][HH];
  for (int m = 0; m < 8; ++m) hs[m][g] = h[(size_t)(r0 + m) * HH + g];
  __syncthreads();
  float acc[8] = {0, 0, 0, 0, 0, 0, 0, 0};
#pragma unroll 4
  for (int k = 0; k < HH; ++k) {
    float w = gcn_WT[k * HH + g];
#pragma unroll
    for (int m = 0; m < 8; ++m) acc[m] += hs[m][k] * w;
  }
  for (int m = 0; m < 8; ++m) xw[(size_t)(r0 + m) * HH + g] = acc[m];
}

// scatter: agg[b,dst,:] += xw[b,src,:] * norm(e); thread = (edge, channel)
__global__ void scatter_kernel(const int* __restrict__ ei, const float* __restrict__ xw,
                               const float* __restrict__ dinv, float* __restrict__ agg) {
  int gid = blockIdx.x * 256 + threadIdx.x;
  int e = gid >> 7;
  int jj = gid & 127;
  if (e >= EE) return;
  int s = ei[e];
  int d = ei[EE + e];
  float nrm = dinv[s] * dinv[d];
#pragma unroll
  for (int b = 0; b < NB; ++b) {
    float v = xw[((size_t)b * NN + s) * HH + jj] * nrm;
    atomicAdd(&agg[((size_t)b * NN + d) * HH + jj], v);
  }
}

// final: add self-loop + bias, relu, two dot heads. one wave per row.
__global__ __launch_bounds__(256) void final_kernel(
    const float* __restrict__ agg, const float* __restrict__ xw, const float* __restrict__ dinv,
    const float* __restrict__ gcn_b, const float* __restrict__ fcw_c, const float* __restrict__ fcb_c,
    const float* __restrict__ fcw_i, const float* __restrict__ fcb_i, float* __restrict__ out) {
  int row = blockIdx.x * 4 + (threadIdx.x >> 6);
  int lane = threadIdx.x & 63;
  int n = row % NN;
  float sn = dinv[n] * dinv[n];
  float sc = 0.0f, si = 0.0f;
  for (int jj = lane; jj < HH; jj += 64) {
    float v = agg[(size_t)row * HH + jj] + xw[(size_t)row * HH + jj] * sn + gcn_b[jj];
    v = fmaxf(v, 0.0f);
    sc += v * fcw_c[jj];
    si += v * fcw_i[jj];
  }
#pragma unroll
  for (int off = 32; off > 0; off >>= 1) {
    sc += __shfl_down(sc, off);
    si += __shfl_down(si, off);
  }
  if (lane == 0) {
    out[row] = sc + fcb_c[0];
    out[NB * NN + row] = si + fcb_i[0];
  }
}

extern "C" void kernel_launch(void* const* d_in, const int* in_sizes, int n_in,
                              void* d_out, int out_size, void* d_ws, size_t ws_size,
                              hipStream_t stream) {
  const float* x     = (const float*)d_in[0];
  const int*   ei    = (const int*)d_in[1];
  const float* W_ih  = (const float*)d_in[2];
  const float* W_hh  = (const float*)d_in[3];
  const float* b_ih  = (const float*)d_in[4];
  const float* b_hh  = (const float*)d_in[5];
  const float* gcn_W = (const float*)d_in[6];
  const float* gcn_b = (const float*)d_in[7];
  const float* fcw_c = (const float*)d_in[8];
  const float* fcb_c = (const float*)d_in[9];
  const float* fcw_i = (const float*)d_in[10];
  const float* fcb_i = (const float*)d_in[11];
  float* out = (float*)d_out;

  char* cur = (char*)d_ws;
  unsigned short* Wbh_hi = (unsigned short*)cur; cur += 65536 * 2;
  unsigned short* Wbh_lo = (unsigned short*)cur; cur += 65536 * 2;
  unsigned short* Wbi_hi = (unsigned short*)cur; cur += 16384 * 2;
  unsigned short* Wbi_lo = (unsigned short*)cur; cur += 16384 * 2;
  float* gcn_WT = (float*)cur; cur += 16384 * 4;
  float* bias   = (float*)cur; cur += 512 * 4;
  float* deg    = (float*)cur; cur += 4000 * 4;
  float* dinv   = (float*)cur; cur += 4000 * 4;
  float* h_all  = (float*)cur; cur += (size_t)4096000 * 4;
  float* xw     = (float*)cur; cur += (size_t)4096000 * 4;
  float* agg    = (float*)cur; cur += (size_t)4096000 * 4;

  setup_kernel<<<402, 256, 0, stream>>>(W_ih, W_hh, b_ih, b_hh, gcn_W,
                                        Wbh_hi, Wbh_lo, Wbi_hi, Wbi_lo,
                                        gcn_WT, bias, deg);
  hipMemsetAsync(agg, 0, (size_t)4096000 * sizeof(float), stream);
  lstm_kernel<<<(NB * NN) / 64, 512, 0, stream>>>(x, Wbh_hi, Wbh_lo, Wbi_hi, Wbi_lo,
                                                  bias, h_all);
  deg_kernel<<<EE / 256, 256, 0, stream>>>(ei, deg);
  dinv_kernel<<<(NN + 255) / 256, 256, 0, stream>>>(deg, dinv);
  xw_kernel<<<(NB * NN) / 8, 128, 0, stream>>>(h_all, gcn_WT, xw);
  scatter_kernel<<<(EE * 128) / 256, 256, 0, stream>>>(ei, xw, dinv, agg);
  final_kernel<<<(NB * NN) / 4, 256, 0, stream>>>(agg, xw, dinv, gcn_b, fcw_c, fcb_c,
                                                  fcw_i, fcb_i, out);
}

// Round 7
// 664.496 us; speedup vs baseline: 2.1072x; 1.4041x over previous
//
#include <hip/hip_runtime.h>

#define NB 8
#define TT 24
#define NN 4000
#define FF 32
#define HH 128
#define EE 64000

typedef float f32x4 __attribute__((ext_vector_type(4)));
typedef short bf16x8 __attribute__((ext_vector_type(8)));
#define MFMA16(a, b, c) __builtin_amdgcn_mfma_f32_16x16x32_bf16(a, b, c, 0, 0, 0)

// fast gate math: v_exp + v_rcp (rel err ~1e-7, negligible vs bf16-split error)
__device__ __forceinline__ float fsig(float x) {
  return __builtin_amdgcn_rcpf(1.0f + __expf(-x));
}
__device__ __forceinline__ float ftanh(float x) {
  return 1.0f - 2.0f * __builtin_amdgcn_rcpf(__expf(2.0f * x) + 1.0f);
}

// round-to-nearest-even fp32 -> bf16; returns bits, sets *hif to the bf16 value as fp32
__device__ __forceinline__ unsigned short rne16(float x, float* hif) {
  unsigned u = __float_as_uint(x);
  unsigned r = (u + 0x7FFFu + ((u >> 16) & 1u)) >> 16;
  *hif = __uint_as_float(r << 16);
  return (unsigned short)r;
}

// ---------- setup: pack weights into MFMA fragment order (hi/lo split), combine bias, init deg ----------
__global__ void setup_kernel(const float* __restrict__ W_ih, const float* __restrict__ W_hh,
                             const float* __restrict__ b_ih, const float* __restrict__ b_hh,
                             const float* __restrict__ gcn_W,
                             unsigned short* __restrict__ Wbh_hi, unsigned short* __restrict__ Wbh_lo,
                             unsigned short* __restrict__ Wbi_hi, unsigned short* __restrict__ Wbi_lo,
                             float* __restrict__ gcn_WT, float* __restrict__ bias,
                             float* __restrict__ deg) {
  int idx = blockIdx.x * 256 + threadIdx.x;
  if (idx < 65536) {
    int e = idx & 7, l = (idx >> 3) & 63, ks = (idx >> 9) & 3, nt = idx >> 11;
    int gate = nt * 16 + (l & 15);
    int k = ks * 32 + (l >> 4) * 8 + e;
    float wv = W_hh[gate * 128 + k];
    float hif, d;
    unsigned short hb = rne16(wv, &hif);
    unsigned short lb = rne16(wv - hif, &d);
    Wbh_hi[idx] = hb;
    Wbh_lo[idx] = lb;
  } else if (idx < 65536 + 16384) {
    int p = idx - 65536;
    int e = p & 7, l = (p >> 3) & 63, nt = p >> 9;
    int gate = nt * 16 + (l & 15);
    int k = (l >> 4) * 8 + e;
    float wv = W_ih[gate * 32 + k];
    float hif, d;
    unsigned short hb = rne16(wv, &hif);
    unsigned short lb = rne16(wv - hif, &d);
    Wbi_hi[p] = hb;
    Wbi_lo[p] = lb;
  } else if (idx < 65536 + 16384 + 16384) {
    int p = idx - 65536 - 16384;
    int g = p & 127, k = p >> 7;
    gcn_WT[p] = gcn_W[g * 128 + k];
  } else if (idx < 65536 + 16384 + 16384 + 512) {
    int g = idx - (65536 + 16384 + 16384);
    bias[g] = b_ih[g] + b_hh[g];
  } else if (idx < 65536 + 16384 + 16384 + 512 + NN) {
    int n = idx - (65536 + 16384 + 16384 + 512);
    deg[n] = 1.0f;  // self-loop
  }
}

// ---------- x pre-split: B-fragment-ready bf16 hi/lo ----------
// xpk elem offset = (rt*TT + t)*1024 + s*512 + l*8 ; rt = global row-tile (16 rows), s in {hi=0,lo=1}
__global__ __launch_bounds__(256) void xsplit_kernel(const float* __restrict__ x,
                                                     unsigned short* __restrict__ xpk) {
  int gid = blockIdx.x * 256 + threadIdx.x;  // exactly 2000*24*64
  int l = gid & 63;
  int t = (gid >> 6) % TT;
  int rt = gid / (TT * 64);
  int col = l & 15, kc = l >> 4;
  int r = rt * 16 + col;              // NN%16==0 -> tile never straddles batch
  int b = (rt * 16) / NN;
  int n = r - b * NN;
  const float* src = x + (((size_t)b * TT + t) * NN + n) * FF + kc * 8;
  float4 p0 = *(const float4*)src;
  float4 p1 = *(const float4*)(src + 4);
  float xf[8] = {p0.x, p0.y, p0.z, p0.w, p1.x, p1.y, p1.z, p1.w};
  bf16x8 vh, vl;
#pragma unroll
  for (int e = 0; e < 8; ++e) {
    float hif, d;
    vh[e] = (short)rne16(xf[e], &hif);
    vl[e] = (short)rne16(xf[e] - hif, &d);
  }
  size_t ob = (size_t)(rt * TT + t) * 1024 + l * 8;
  *(bf16x8*)(xpk + ob) = vh;
  *(bf16x8*)(xpk + ob + 512) = vl;
}

// ---------- LSTM via split-bf16 MFMA, swapped operands: D[gate][seq] ----------
// 8 waves, 64 seqs/block. Wave w owns gates {128g + 16w + [0,16)} for g=0..3.
__global__ __launch_bounds__(512) void lstm_kernel(
    const unsigned short* __restrict__ xpk,  // pre-split x fragments
    const unsigned short* __restrict__ Wbh_hi, const unsigned short* __restrict__ Wbh_lo,
    const unsigned short* __restrict__ Wbi_hi, const unsigned short* __restrict__ Wbi_lo,
    const float* __restrict__ bias,          // [512] combined
    float* __restrict__ h_out)               // [B*N, H] fp32
{
  __shared__ unsigned short hbuf[2][2][64 * 128];  // [buf][hi/lo][row*128+j] : 64 KB
  const int tid = threadIdx.x;
  const int w = tid >> 6, l = tid & 63;
  const int col = l & 15, kc = l >> 4;
  const int j0 = 16 * w + 4 * kc;
  const int r0 = blockIdx.x * 64;

  // zero h(0) buffer (both splits)
  {
    uint4* p0 = (uint4*)&hbuf[0][0][0];
    for (int i = tid; i < 2048; i += 512) p0[i] = make_uint4(0, 0, 0, 0);
  }

  f32x4 bq[4];
#pragma unroll
  for (int g = 0; g < 4; ++g) bq[g] = *(const f32x4*)(bias + g * 128 + j0);

  float c[4][4];
#pragma unroll
  for (int sq = 0; sq < 4; ++sq)
#pragma unroll
    for (int r = 0; r < 4; ++r) c[sq][r] = 0.0f;

  const unsigned short* xb0 = xpk + (size_t)(r0 >> 4) * (TT * 1024) + l * 8;

  __syncthreads();

  for (int t = 0; t < TT; ++t) {
    const char* hr_hi = (const char*)&hbuf[t & 1][0][0];
    const char* hr_lo = (const char*)&hbuf[t & 1][1][0];
    char* hw_hi = (char*)&hbuf[(t + 1) & 1][0][0];
    char* hw_lo = (char*)&hbuf[(t + 1) & 1][1][0];

    f32x4 acc[4][4];
#pragma unroll
    for (int sq = 0; sq < 4; ++sq)
#pragma unroll
      for (int g = 0; g < 4; ++g) acc[sq][g] = bq[g];  // bias-seeded

    // ---- recurrence: W_hh(A) x h(B), split-bf16 (3 MFMA per tile-pair) ----
#pragma unroll
    for (int ks = 0; ks < 4; ++ks) {
      bf16x8 bh[4], bl_[4];
#pragma unroll
      for (int sq = 0; sq < 4; ++sq) {
        int off = (16 * sq + col) * 256 + (((4 * ks + kc) ^ col) << 4);
        bh[sq] = *(const bf16x8*)(hr_hi + off);
        bl_[sq] = *(const bf16x8*)(hr_lo + off);
      }
#pragma unroll
      for (int g = 0; g < 4; ++g) {
        size_t wo = ((size_t)((g * 8 + w) * 4 + ks) * 64 + l) * 8;
        bf16x8 wh = *(const bf16x8*)(Wbh_hi + wo);
        bf16x8 wl = *(const bf16x8*)(Wbh_lo + wo);
#pragma unroll
        for (int sq = 0; sq < 4; ++sq) {
          acc[sq][g] = MFMA16(wh, bh[sq], acc[sq][g]);
          acc[sq][g] = MFMA16(wh, bl_[sq], acc[sq][g]);
          acc[sq][g] = MFMA16(wl, bh[sq], acc[sq][g]);
        }
      }
    }

    // ---- x(t) fragments: pre-split, loaded directly (issued after hh weights) ----
    bf16x8 xh[4], xl[4];
#pragma unroll
    for (int sq = 0; sq < 4; ++sq) {
      const unsigned short* xb = xb0 + (size_t)sq * (TT * 1024) + t * 1024;
      xh[sq] = *(const bf16x8*)xb;
      xl[sq] = *(const bf16x8*)(xb + 512);
    }

    // ---- input projection: W_ih(A) x x(B) ----
#pragma unroll
    for (int g = 0; g < 4; ++g) {
      size_t wo = ((size_t)(g * 8 + w) * 64 + l) * 8;
      bf16x8 wh = *(const bf16x8*)(Wbi_hi + wo);
      bf16x8 wl = *(const bf16x8*)(Wbi_lo + wo);
#pragma unroll
      for (int sq = 0; sq < 4; ++sq) {
        acc[sq][g] = MFMA16(wh, xh[sq], acc[sq][g]);
        acc[sq][g] = MFMA16(wh, xl[sq], acc[sq][g]);
        acc[sq][g] = MFMA16(wl, xh[sq], acc[sq][g]);
      }
    }

    // ---- gates (i,f,g,o) + state update; swizzled b64 writes of split h ----
#pragma unroll
    for (int sq = 0; sq < 4; ++sq) {
      unsigned long long phi = 0ull, plo = 0ull;
      float hv[4];
#pragma unroll
      for (int r = 0; r < 4; ++r) {
        float iv = fsig(acc[sq][0][r]);
        float fv = fsig(acc[sq][1][r]);
        float gv = ftanh(acc[sq][2][r]);
        float ov = fsig(acc[sq][3][r]);
        float cc = fv * c[sq][r] + iv * gv;
        c[sq][r] = cc;
        float hh = ov * ftanh(cc);
        hv[r] = hh;
        // truncation split: hi = trunc-to-bf16, lo = rne(h - hi)
        unsigned u = __float_as_uint(hh);
        unsigned short hb = (unsigned short)(u >> 16);
        float hif = __uint_as_float(u & 0xFFFF0000u);
        float d;
        unsigned short lb = rne16(hh - hif, &d);
        phi |= (unsigned long long)hb << (16 * r);
        plo |= (unsigned long long)lb << (16 * r);
      }
      int row = 16 * sq + col;
      int cs = ((2 * w + (kc >> 1)) ^ col);
      int woff = row * 256 + cs * 16 + 8 * (kc & 1);
      *(unsigned long long*)(hw_hi + woff) = phi;
      *(unsigned long long*)(hw_lo + woff) = plo;
      if (t == TT - 1) {
        *(float4*)&h_out[(size_t)(r0 + 16 * sq + col) * HH + j0] =
            make_float4(hv[0], hv[1], hv[2], hv[3]);
      }
    }
    __syncthreads();
  }
}

// ---------- GCN ----------
__global__ void deg_kernel(const int* __restrict__ ei, float* __restrict__ deg) {
  int e = blockIdx.x * 256 + threadIdx.x;
  if (e < EE) atomicAdd(&deg[ei[EE + e]], 1.0f);  // dst row
}

__global__ void dinv_kernel(const float* __restrict__ deg, float* __restrict__ dinv) {
  int n = blockIdx.x * 256 + threadIdx.x;
  if (n < NN) dinv[n] = 1.0f / sqrtf(deg[n]);  // deg >= 1 (self loop)
}

// xw[b,n,g] = sum_k h[b,n,k] * gcn_W[g,k]  ; 8 rows per block
__global__ __launch_bounds__(128) void xw_kernel(const float* __restrict__ h,
                                                 const float* __restrict__ gcn_WT,
                                                 float* __restrict__ xw) {
  const int r0 = blockIdx.x * 8;
  const int g = threadIdx.x;
  __shared__ float hs[8][HH];
  for (int m = 0; m < 8; ++m) hs[m][g] = h[(size_t)(r0 + m) * HH + g];
  __syncthreads();
  float acc[8] = {0, 0, 0, 0, 0, 0, 0, 0};
#pragma unroll 4
  for (int k = 0; k < HH; ++k) {
    float w = gcn_WT[k * HH + g];
#pragma unroll
    for (int m = 0; m < 8; ++m) acc[m] += hs[m][k] * w;
  }
  for (int m = 0; m < 8; ++m) xw[(size_t)(r0 + m) * HH + g] = acc[m];
}

// scatter: agg[b,dst,:] += xw[b,src,:] * norm(e); thread = (edge, channel)
__global__ void scatter_kernel(const int* __restrict__ ei, const float* __restrict__ xw,
                               const float* __restrict__ dinv, float* __restrict__ agg) {
  int gid = blockIdx.x * 256 + threadIdx.x;
  int e = gid >> 7;
  int jj = gid & 127;
  if (e >= EE) return;
  int s = ei[e];
  int d = ei[EE + e];
  float nrm = dinv[s] * dinv[d];
#pragma unroll
  for (int b = 0; b < NB; ++b) {
    float v = xw[((size_t)b * NN + s) * HH + jj] * nrm;
    atomicAdd(&agg[((size_t)b * NN + d) * HH + jj], v);
  }
}

// final: add self-loop + bias, relu, two dot heads. one wave per row.
__global__ __launch_bounds__(256) void final_kernel(
    const float* __restrict__ agg, const float* __restrict__ xw, const float* __restrict__ dinv,
    const float* __restrict__ gcn_b, const float* __restrict__ fcw_c, const float* __restrict__ fcb_c,
    const float* __restrict__ fcw_i, const float* __restrict__ fcb_i, float* __restrict__ out) {
  int row = blockIdx.x * 4 + (threadIdx.x >> 6);
  int lane = threadIdx.x & 63;
  int n = row % NN;
  float sn = dinv[n] * dinv[n];
  float sc = 0.0f, si = 0.0f;
  for (int jj = lane; jj < HH; jj += 64) {
    float v = agg[(size_t)row * HH + jj] + xw[(size_t)row * HH + jj] * sn + gcn_b[jj];
    v = fmaxf(v, 0.0f);
    sc += v * fcw_c[jj];
    si += v * fcw_i[jj];
  }
#pragma unroll
  for (int off = 32; off > 0; off >>= 1) {
    sc += __shfl_down(sc, off);
    si += __shfl_down(si, off);
  }
  if (lane == 0) {
    out[row] = sc + fcb_c[0];
    out[NB * NN + row] = si + fcb_i[0];
  }
}

extern "C" void kernel_launch(void* const* d_in, const int* in_sizes, int n_in,
                              void* d_out, int out_size, void* d_ws, size_t ws_size,
                              hipStream_t stream) {
  const float* x     = (const float*)d_in[0];
  const int*   ei    = (const int*)d_in[1];
  const float* W_ih  = (const float*)d_in[2];
  const float* W_hh  = (const float*)d_in[3];
  const float* b_ih  = (const float*)d_in[4];
  const float* b_hh  = (const float*)d_in[5];
  const float* gcn_W = (const float*)d_in[6];
  const float* gcn_b = (const float*)d_in[7];
  const float* fcw_c = (const float*)d_in[8];
  const float* fcb_c = (const float*)d_in[9];
  const float* fcw_i = (const float*)d_in[10];
  const float* fcb_i = (const float*)d_in[11];
  float* out = (float*)d_out;

  char* cur = (char*)d_ws;
  unsigned short* Wbh_hi = (unsigned short*)cur; cur += 65536 * 2;
  unsigned short* Wbh_lo = (unsigned short*)cur; cur += 65536 * 2;
  unsigned short* Wbi_hi = (unsigned short*)cur; cur += 16384 * 2;
  unsigned short* Wbi_lo = (unsigned short*)cur; cur += 16384 * 2;
  float* gcn_WT = (float*)cur; cur += 16384 * 4;
  float* bias   = (float*)cur; cur += 512 * 4;
  float* deg    = (float*)cur; cur += 4000 * 4;
  float* dinv   = (float*)cur; cur += 4000 * 4;
  float* h_all  = (float*)cur; cur += (size_t)4096000 * 4;
  // overlay region: xpk (98.3 MB, live only during lstm) | xw+agg (live after lstm)
  unsigned short* xpk = (unsigned short*)cur;           // 2000*24*2*512 ushorts
  float* xw  = (float*)cur;                              // 4,096,000 floats
  float* agg = xw + 4096000;                             // 4,096,000 floats

  setup_kernel<<<402, 256, 0, stream>>>(W_ih, W_hh, b_ih, b_hh, gcn_W,
                                        Wbh_hi, Wbh_lo, Wbi_hi, Wbi_lo,
                                        gcn_WT, bias, deg);
  xsplit_kernel<<<(2000 * TT * 64) / 256, 256, 0, stream>>>(x, xpk);
  lstm_kernel<<<(NB * NN) / 64, 512, 0, stream>>>(xpk, Wbh_hi, Wbh_lo, Wbi_hi, Wbi_lo,
                                                  bias, h_all);
  // xpk dead from here; agg/xw reuse its space
  hipMemsetAsync(agg, 0, (size_t)4096000 * sizeof(float), stream);
  deg_kernel<<<EE / 256, 256, 0, stream>>>(ei, deg);
  dinv_kernel<<<(NN + 255) / 256, 256, 0, stream>>>(deg, dinv);
  xw_kernel<<<(NB * NN) / 8, 128, 0, stream>>>(h_all, gcn_WT, xw);
  scatter_kernel<<<(EE * 128) / 256, 256, 0, stream>>>(ei, xw, dinv, agg);
  final_kernel<<<(NB * NN) / 4, 256, 0, stream>>>(agg, xw, dinv, gcn_b, fcw_c, fcb_c,
                                                  fcw_i, fcb_i, out);
}